// Round 7
// baseline (304.180 us; speedup 1.0000x reference)
//
#include <hip/hip_runtime.h>
#include <math.h>

#define BLOCK 256
#define H16 0.0625f
#define SENT 1e30f

typedef float f32x4 __attribute__((ext_vector_type(4)));

// ---------------------------------------------------------------------------
// Host-side reproduction of B_NP = Vh[rank:].T from numpy.linalg.svd(L).
// For (m,n)=(15,32) with n >= mnthr(=int(15*11/6)=27), LAPACK dgesdd takes
// Path 9t (LQ first): rows 15..31 of Vh are exactly rows 15..31 of the full
// orthogonal factor Q from the Householder LQ factorization of L
// (dgelqf + dorglq), untouched by the bidiagonal-SVD stage. Reproduce
// dgelq2/dlarfg in double precision; dorgl2 applies H(15) first..H(1) last.
// ---------------------------------------------------------------------------
struct BMat { float v[32][17]; };
static BMat g_B;

static struct BInitializer {
  BInitializer() {
    double A[15][32];
    for (int r = 0; r < 15; ++r)
      for (int j = 0; j < 32; ++j) A[r][j] = 0.0;
    for (int k = 1; k <= 15; ++k) {
      double xk = (double)k / 16.0;
      A[k - 1][2 * (k - 1)]     =  xk;
      A[k - 1][2 * (k - 1) + 1] =  1.0;
      A[k - 1][2 * k]           = -xk;
      A[k - 1][2 * k + 1]       = -1.0;
    }
    double V[15][32], tau[15];
    for (int i = 0; i < 15; ++i) {
      double alpha = A[i][i];
      double xn2 = 0.0;
      for (int j = i + 1; j < 32; ++j) xn2 += A[i][j] * A[i][j];
      for (int j = 0; j < 32; ++j) V[i][j] = 0.0;
      V[i][i] = 1.0;
      if (xn2 == 0.0) { tau[i] = 0.0; continue; }
      double beta = -copysign(sqrt(alpha * alpha + xn2), alpha);
      tau[i] = (beta - alpha) / beta;
      double s = 1.0 / (alpha - beta);
      for (int j = i + 1; j < 32; ++j) V[i][j] = A[i][j] * s;
      A[i][i] = beta;
      for (int r = i + 1; r < 15; ++r) {
        double dot = 0.0;
        for (int j = i; j < 32; ++j) dot += A[r][j] * V[i][j];
        double t = tau[i] * dot;
        for (int j = i; j < 32; ++j) A[r][j] -= t * V[i][j];
      }
    }
    for (int q = 0; q < 17; ++q) {
      double u[32];
      for (int p = 0; p < 32; ++p) u[p] = 0.0;
      u[15 + q] = 1.0;
      for (int i = 14; i >= 0; --i) {
        double dot = 0.0;
        for (int p = i; p < 32; ++p) dot += u[p] * V[i][p];
        double t = tau[i] * dot;
        for (int p = i; p < 32; ++p) u[p] -= t * V[i][p];
      }
      for (int p = 0; p < 32; ++p) g_B.v[p][q] = (float)u[p];
    }
  }
} g_binit;

// ---------------------------------------------------------------------------
// Closed-form CPAB flow. Packed per-boundary table (flat-indexed, 34 entries)
//   Gf[d*17+k] = { vb_k, log(vb_k), pr_k (prefix of clamped cell times), a }
// d=0 forward, d=1 mirrored (y=1-x: a'=a_{15-c}, b'=-(a+b)_{15-c}).
// NOTE: kernel_launch launches this 3x (instrumentation: dur_us = ovh + 3k,
// isolates kernel time k from the harness restore/poison overhead).
// ---------------------------------------------------------------------------
__global__ __launch_bounds__(BLOCK) void
cpab_kernel(const f32x4* __restrict__ x4, const float* __restrict__ theta,
            f32x4* __restrict__ zout, f32x4* __restrict__ pout, BMat B) {
  __shared__ float Ash[32];
  __shared__ float4 G[2][17];

  const int tid = threadIdx.x;
  const float4* Gf = &G[0][0];

  // step 1: A = theta @ B.T (32 lanes)
  if (tid < 32) {
    float acc = 0.0f;
#pragma unroll
    for (int q = 0; q < 17; ++q) acc += theta[q] * B.v[tid][q];
    Ash[tid] = acc;
  }
  __syncthreads();

  // step 2: boundary velocity, log, owning-cell slope (34 lanes)
  if (tid < 34) {
    int d = (tid >= 17) ? 1 : 0, k = d ? tid - 17 : tid;
    int c = min(k, 15), cs = d ? 15 - c : c;
    float a = Ash[2 * cs];
    float b = d ? -(Ash[2 * cs] + Ash[2 * cs + 1]) : Ash[2 * cs + 1];
    float v = fmaf(a, (float)k * H16, b);
    G[d][k].x = v;
    G[d][k].y = __logf(v);
    G[d][k].w = a;
  }
  __syncthreads();

  // step 3: per-cell traversal times + prefix, 1 lane per direction,
  // batch-read into registers (single LDS wait; no serial read chain)
  if (tid < 2) {
    int d = tid;
    float vv[17], ll[17], aa[17];
#pragma unroll
    for (int k = 0; k < 17; ++k) {
      float4 g = G[d][k];
      vv[k] = g.x; ll[k] = g.y; aa[k] = g.w;
    }
    float s = 0.0f;
    G[d][0].z = 0.0f;
#pragma unroll
    for (int c = 0; c < 16; ++c) {
      float tau;
      if (vv[c] > 0.0f && vv[c + 1] > 0.0f) {
        bool az = fabsf(aa[c]) < 1e-12f;
        tau = az ? H16 / vv[c] : (ll[c + 1] - ll[c]) / aa[c];
      } else {
        tau = 2.0f;
      }
      tau = fminf(fmaxf(tau, 0.0f), 2.0f);
      s += tau;                 // clamped to [0,2]; 2 == blocked/over-budget
      G[d][c + 1].z = s;
    }
  }
  __syncthreads();

  const int gid = blockIdx.x * BLOCK + tid;
  const f32x4 xs = __builtin_nontemporal_load(x4 + gid);
  float xi[4] = {xs.x, xs.y, xs.z, xs.w};

  // ---- stage A: clamp, cell index, g0 reads ----
  float xcl[4]; int c0[4]; float4 g0[4];
#pragma unroll
  for (int p = 0; p < 4; ++p) {
    xcl[p] = fminf(fmaxf(xi[p], 1e-7f), 1.0f - 1e-7f);
    c0[p] = min((int)(xcl[p] * 16.0f), 15);
    g0[p] = Gf[c0[p]];
  }

  // ---- stage B: direction + transcendentals; gb + coarse probes ----
  float xw[4], v0[4], lv0[4], ia[4], rv[4];
  int cw[4], bd[4];
  bool mir[4], az[4];
  float4 gb[4];
  float pc4[4], pc8[4], pc12[4];
#pragma unroll
  for (int p = 0; p < 4; ++p) {
    float a = g0[p].w;
    float xr = fmaf(-H16, (float)c0[p], xcl[p]);     // x - c0*h (exact)
    float vraw = fmaf(a, xr, g0[p].x);
    mir[p] = vraw < 0.0f;
    v0[p] = fabsf(vraw);                             // |v| in working coords
    xw[p] = mir[p] ? 1.0f - xcl[p] : xcl[p];
    cw[p] = mir[p] ? 15 - c0[p] : c0[p];
    bd[p] = mir[p] ? 17 : 0;                         // flat base index
    lv0[p] = __logf(v0[p]);
    az[p] = fabsf(a) < 1e-12f;
    ia[p] = __builtin_amdgcn_rcpf(az[p] ? 1.0f : a);
    rv[p] = __builtin_amdgcn_rcpf(fmaxf(v0[p], 1e-30f));
    gb[p] = Gf[bd[p] + cw[p] + 1];
    pc4[p]  = Gf[bd[p] + 4].z;
    pc8[p]  = Gf[bd[p] + 8].z;
    pc12[p] = Gf[bd[p] + 12].z;
  }

  // ---- stage C: t0/Tstar, quadrant; fine probes ----
  float Tst[4]; int q[4]; float f1[4], f2[4], f3[4];
#pragma unroll
  for (int p = 0; p < 4; ++p) {
    float xb = (float)(cw[p] + 1) * H16;
    float t0 = az[p] ? (xb - xw[p]) * rv[p] : (gb[p].y - lv0[p]) * ia[p];
    if (v0[p] < 1e-15f || gb[p].x <= 0.0f) t0 = SENT;  // stationary/blocked
    float T = 1.0f - t0 + gb[p].z;
    Tst[p] = T;
    int qq = 0;
    qq = (pc4[p]  <= T) ? 4  : qq;
    qq = (pc8[p]  <= T) ? 8  : qq;
    qq = (pc12[p] <= T) ? 12 : qq;
    q[p] = qq;
    f1[p] = Gf[bd[p] + qq + 1].z;
    f2[p] = Gf[bd[p] + qq + 2].z;
    f3[p] = Gf[bd[p] + qq + 3].z;
  }

  // ---- stage D: final cell; gm ----
  int mf[4]; bool moved[4]; float4 gm[4];
#pragma unroll
  for (int p = 0; p < 4; ++p) {
    float T = Tst[p];
    int m = q[p] + (f1[p] <= T) + (f2[p] <= T) + (f3[p] <= T);
    moved[p] = m > cw[p];
    mf[p] = moved[p] ? m : cw[p];
    gm[p] = Gf[bd[p] + mf[p]];
  }

  // ---- stage E: closed-form finish ----
  float zr[4], ph[4];
#pragma unroll
  for (int p = 0; p < 4; ++p) {
    float am = gm[p].w;
    bool az3 = fabsf(am) < 1e-12f;
    float iam = __builtin_amdgcn_rcpf(az3 ? 1.0f : am);
    float mfh = (float)mf[p] * H16;
    float boa = fmaf(gm[p].x, iam, -mfh);            // b/a from left boundary
    float t_rem = moved[p] ? Tst[p] - gm[p].z : 1.0f;
    float xe = moved[p] ? mfh : xw[p];
    float ve = moved[p] ? gm[p].x : v0[p];
    float zw = az3 ? fmaf(ve, t_rem, xe)
                   : fmaf(xe + boa, __expf(am * t_rem), -boa);
    zr[p] = mir[p] ? 1.0f - zw : zw;
    ph[p] = (moved[p] ? gm[p].y - lv0[p] : 0.0f) + am * t_rem;
  }

  f32x4 zv = {zr[0], zr[1], zr[2], zr[3]};
  f32x4 pv = {ph[0], ph[1], ph[2], ph[3]};
  __builtin_nontemporal_store(zv, zout + gid);
  __builtin_nontemporal_store(pv, pout + gid);
}

extern "C" void kernel_launch(void* const* d_in, const int* in_sizes, int n_in,
                              void* d_out, int out_size, void* d_ws, size_t ws_size,
                              hipStream_t stream) {
  const f32x4* x4 = (const f32x4*)d_in[0];
  const float* theta = (const float*)d_in[1];
  float* out = (float*)d_out;
  const int npts = in_sizes[0];  // 16777216
  const int groups = npts / 4;
  const int grid = groups / BLOCK;
  // Instrumentation: 3 identical launches (idempotent; same work every call).
  // dur_us = harness_overhead + 3*kernel_time -> isolates kernel_time.
  for (int rep = 0; rep < 3; ++rep) {
    cpab_kernel<<<grid, BLOCK, 0, stream>>>(
        x4, theta, (f32x4*)out, (f32x4*)(out + npts), g_B);
  }
}